// Round 9
// baseline (591.259 us; speedup 1.0000x reference)
//
#include <hip/hip_runtime.h>
#include <hip/hip_fp16.h>
#include <cstdio>

constexpr int NPB = 512;      // nodes per bucket (power of 2)
constexpr int BSH = 9;        // log2(NPB)
constexpr int BIN_CHUNK = 8192;  // edges per block in binning passes (LDS reorder buffer)
constexpr int CAP = 18432;    // LDS staging entries in buildcsr (72KB)

__device__ __forceinline__ float2 h2f(int bits) {
  __half2 h;
  *reinterpret_cast<int*>(&h) = bits;
  return __half22float2(h);
}
__device__ __forceinline__ int f2h(float a, float b) {
  __half2 h = __floats2half2_rn(a, b);
  return *reinterpret_cast<int*>(&h);
}

// ---------------- bucketed CSR build (zero per-edge global atomics, coalesced shuffle) -------

__global__ __launch_bounds__(256) void k_histpb(const int* __restrict__ dst, int* __restrict__ hist,
                                                int E, int nblocks, int nbuck) {
  __shared__ int h[512];
  int t = threadIdx.x;
  h[t] = 0;
  h[t + 256] = 0;
  __syncthreads();
  int e0 = blockIdx.x * BIN_CHUNK + t;
  int eend = min(E, (blockIdx.x + 1) * BIN_CHUNK);
  for (int e = e0; e < eend; e += 256) atomicAdd(&h[dst[e] >> BSH], 1);
  __syncthreads();
  for (int b = t; b < nbuck; b += 256) hist[(size_t)b * nblocks + blockIdx.x] = h[b];
}

__global__ __launch_bounds__(256) void k_scanA(const int* __restrict__ in, int* __restrict__ out,
                                               int* __restrict__ bsum, int n) {
  int base = blockIdx.x * 2048 + threadIdx.x * 8;
  int v[8];
  int run = 0;
#pragma unroll
  for (int i = 0; i < 8; ++i) { int idx = base + i; v[i] = (idx < n) ? in[idx] : 0; }
#pragma unroll
  for (int i = 0; i < 8; ++i) { int t = v[i]; v[i] = run; run += t; }
  __shared__ int s[256];
  s[threadIdx.x] = run;
  __syncthreads();
  for (int off = 1; off < 256; off <<= 1) {
    int t = (threadIdx.x >= off) ? s[threadIdx.x - off] : 0;
    __syncthreads();
    s[threadIdx.x] += t;
    __syncthreads();
  }
  int toff = s[threadIdx.x] - run;
#pragma unroll
  for (int i = 0; i < 8; ++i) { int idx = base + i; if (idx < n) out[idx] = v[i] + toff; }
  if (threadIdx.x == 255) bsum[blockIdx.x] = s[255];
}

__global__ __launch_bounds__(1024) void k_scanB(int* bsum, int nb) {
  __shared__ int s[1024];
  int t = threadIdx.x;
  int v = (t < nb) ? bsum[t] : 0;
  s[t] = v;
  __syncthreads();
  for (int off = 1; off < 1024; off <<= 1) {
    int tv = (t >= off) ? s[t - off] : 0;
    __syncthreads();
    s[t] += tv;
    __syncthreads();
  }
  if (t < nb) bsum[t] = s[t] - v;  // exclusive
}

__global__ __launch_bounds__(256) void k_scanC(int* __restrict__ out, const int* __restrict__ bsum,
                                               int n, int total) {
  int base = blockIdx.x * 2048 + threadIdx.x * 8;
  int add = bsum[blockIdx.x];
#pragma unroll
  for (int i = 0; i < 8; ++i) { int idx = base + i; if (idx < n) out[idx] += add; }
  if (blockIdx.x == 0 && threadIdx.x == 0) out[n] = total;
}

// Pass 2: reorder chunk in LDS (bucket-major), then all-lane coalesced write-out via
// 9-step binary search. 512 threads, 38KB LDS -> 4 blocks/CU.
__global__ __launch_bounds__(512) void k_binR(const int* __restrict__ dst, const int* __restrict__ src,
                                              const int* __restrict__ hist_s, int* __restrict__ bin,
                                              int E, int nblocks, int nbuck) {
  __shared__ int lbuf[BIN_CHUNK];
  __shared__ int ls[512];     // per-bucket exclusive start
  __shared__ int cur[512];    // scatter cursors
  __shared__ int gbase[512];  // global base per bucket for this chunk
  int t = threadIdx.x;
  cur[t] = 0;
  __syncthreads();
  int blk0 = blockIdx.x * BIN_CHUNK;
  int eend = min(E, blk0 + BIN_CHUNK);
  int nent = eend - blk0;
  for (int e = blk0 + t; e < eend; e += 512) atomicAdd(&cur[dst[e] >> BSH], 1);
  __syncthreads();
  int v = cur[t];
  ls[t] = v;
  __syncthreads();
  for (int off = 1; off < 512; off <<= 1) {
    int x = (t >= off) ? ls[t - off] : 0;
    __syncthreads();
    ls[t] += x;
    __syncthreads();
  }
  int excl = ls[t] - v;
  __syncthreads();
  ls[t] = excl;
  cur[t] = excl;
  gbase[t] = (t < nbuck) ? hist_s[(size_t)t * nblocks + blockIdx.x] : 0;
  __syncthreads();
  for (int e = blk0 + t; e < eend; e += 512) {
    int d = dst[e];
    int slot = atomicAdd(&cur[d >> BSH], 1);
    lbuf[slot] = ((d & (NPB - 1)) << 18) | src[e];
  }
  __syncthreads();
  // full-lane write-out: bucket of entry i = last b with ls[b] <= i
  for (int i = t; i < nent; i += 512) {
    int w = lbuf[i];
    int lo = 0;
#pragma unroll
    for (int sh = 256; sh > 0; sh >>= 1) {
      int mid = lo + sh;
      if (mid < 512 && ls[mid] <= i) lo = mid;
    }
    __builtin_nontemporal_store(w, &bin[gbase[lo] + (i - ls[lo])]);
  }
}

// Pass 3: one 1024-thread WG per 512-node bucket. Single count pass + single LDS scatter
// + coalesced dump. 76KB LDS -> 2 blocks/CU (full 2048 thr/CU).
__global__ __launch_bounds__(1024) void k_buildcsr(const int* __restrict__ bin, const int* __restrict__ hist_s,
                                                   int* __restrict__ rowptr, int* __restrict__ csr,
                                                   float* __restrict__ dinv, int N, int Etot, int nblocks) {
  __shared__ int cnt[NPB];
  __shared__ int sc[NPB];
  __shared__ int lbuf[CAP];
  int t = threadIdx.x;
  int b = blockIdx.x;
  int node0 = b << BSH;
  int nn = min(NPB, N - node0);
  int ebeg = hist_s[(size_t)b * nblocks];
  int eend = hist_s[(size_t)(b + 1) * nblocks];
  if (t < NPB) cnt[t] = (t < nn) ? 1 : 0;  // self loop
  __syncthreads();
  for (int p = ebeg + t; p < eend; p += 1024)
    atomicAdd(&cnt[__builtin_nontemporal_load(&bin[p]) >> 18], 1);
  __syncthreads();
  int v = 0;
  if (t < NPB) { v = cnt[t]; sc[t] = v; }
  __syncthreads();
  for (int off = 1; off < NPB; off <<= 1) {
    int x = (t >= off && t < NPB) ? sc[t - off] : 0;
    __syncthreads();
    if (t < NPB) sc[t] += x;
    __syncthreads();
  }
  int excl = (t < NPB) ? (sc[t] - v) : 0;
  int cbase = ebeg + node0;  // preceding buckets are full => node0 self-loops precede
  if (t < nn) {
    rowptr[node0 + t] = cbase + excl;
    dinv[node0 + t] = rsqrtf((float)v);
  }
  int total2 = (eend - ebeg) + nn;
  bool stage = (total2 <= CAP);
  __syncthreads();
  if (t < NPB) cnt[t] = excl + ((t < nn) ? 1 : 0);  // cursor past self loop
  if (t < nn) {
    if (stage) lbuf[excl] = node0 + t;
    else       csr[cbase + excl] = node0 + t;
  }
  __syncthreads();
  for (int p = ebeg + t; p < eend; p += 1024) {
    int w = __builtin_nontemporal_load(&bin[p]);
    int slot = atomicAdd(&cnt[w >> 18], 1);
    if (stage) lbuf[slot] = w & 0x3FFFF;
    else       csr[cbase + slot] = w & 0x3FFFF;
  }
  __syncthreads();
  if (stage)
    for (int i = t; i < total2; i += 1024)
      __builtin_nontemporal_store(lbuf[i], &csr[cbase + i]);
  if (b == 0 && t == 0) rowptr[N] = Etot + N;
}

// ---------------- x @ W1 -> split rows tA (dims 0-7) / tB (dims 8-9), pre-scaled ------------
__global__ __launch_bounds__(256) void k_xw(const float* __restrict__ x, const float* __restrict__ W1,
                                            const float* __restrict__ dinv,
                                            int4* __restrict__ tA, int* __restrict__ tB, int n) {
  int tid = blockIdx.x * 256 + threadIdx.x;
  int sub = tid & 15;
  int rowStart = tid >> 4;
  int rowStride = (gridDim.x * 256) >> 4;
  float w[8][10];
#pragma unroll
  for (int jj = 0; jj < 8; ++jj)
#pragma unroll
    for (int k = 0; k < 10; ++k) w[jj][k] = W1[(sub * 8 + jj) * 10 + k];
  for (int row = rowStart; row < n; row += rowStride) {
    const float* xr = x + (size_t)row * 128 + sub * 8;
    float4 a = *(const float4*)xr;
    float4 b = *(const float4*)(xr + 4);
    float xv[8] = {a.x, a.y, a.z, a.w, b.x, b.y, b.z, b.w};
    float acc[10];
#pragma unroll
    for (int k = 0; k < 10; ++k) acc[k] = 0.f;
#pragma unroll
    for (int jj = 0; jj < 8; ++jj)
#pragma unroll
      for (int k = 0; k < 10; ++k) acc[k] = fmaf(xv[jj], w[jj][k], acc[k]);
#pragma unroll
    for (int off = 1; off < 16; off <<= 1)
#pragma unroll
      for (int k = 0; k < 10; ++k) acc[k] += __shfl_xor(acc[k], off);
    if (sub == 0) {
      float d = dinv[row];
      int4 wv;
      wv.x = f2h(acc[0] * d, acc[1] * d);
      wv.y = f2h(acc[2] * d, acc[3] * d);
      wv.z = f2h(acc[4] * d, acc[5] * d);
      wv.w = f2h(acc[6] * d, acc[7] * d);
      tA[row] = wv;
      tB[row] = f2h(acc[8] * d, acc[9] * d);
    }
  }
}

// ---------------- fused GCN layer (split fp16 rows, pre-scaled; nt csr stream) --------------
template <bool USE_W>
__global__ __launch_bounds__(256) void k_agg10(const int4* __restrict__ tAin, const int* __restrict__ tBin,
                                               __half* __restrict__ tAout, __half* __restrict__ tBout,
                                               const int* __restrict__ csr, const int* __restrict__ rowptr,
                                               const float* __restrict__ dinv_d, const float* __restrict__ dnext,
                                               const float* __restrict__ W, const float* __restrict__ bias,
                                               int n) {
  int tid = blockIdx.x * 256 + threadIdx.x;
  int q = tid >> 4, lane = tid & 15;
  if (q >= n) return;
  int beg = rowptr[q], end = rowptr[q + 1];
  float acc[10];
#pragma unroll
  for (int k = 0; k < 10; ++k) acc[k] = 0.f;
  for (int p = beg + lane; p < end; p += 16) {
    int src = __builtin_nontemporal_load(&csr[p]);
    int4 a = tAin[src];
    int b = tBin[src];
    float2 f0 = h2f(a.x), f1 = h2f(a.y), f2 = h2f(a.z), f3 = h2f(a.w), f4 = h2f(b);
    acc[0] += f0.x; acc[1] += f0.y; acc[2] += f1.x; acc[3] += f1.y;
    acc[4] += f2.x; acc[5] += f2.y; acc[6] += f3.x; acc[7] += f3.y;
    acc[8] += f4.x; acc[9] += f4.y;
  }
#pragma unroll
  for (int off = 1; off < 16; off <<= 1)
#pragma unroll
    for (int k = 0; k < 10; ++k) acc[k] += __shfl_xor(acc[k], off);
  if (lane < 10) {
    float dd = dinv_d[q];
    float dn = dnext[q];
    float o = bias[lane];
    if (USE_W) {
#pragma unroll
      for (int m = 0; m < 10; ++m) o = fmaf(acc[m] * dd, W[m * 10 + lane], o);
    } else {
      o += acc[lane] * dd;
    }
    o = fmaxf(o, 0.f) * dn;
    __half h = __float2half(o);
    if (lane < 8) tAout[((size_t)q << 3) + lane] = h;
    else          tBout[((size_t)q << 1) + (lane - 8)] = h;
  }
}

// ---------------- output layer: probs[q] = dd * sum t5'[src] + bo  (t5' pre-scaled) ----------
__global__ __launch_bounds__(256) void k_agg1(const float* __restrict__ t5, float* __restrict__ probs,
                                              const int* __restrict__ csr, const int* __restrict__ rowptr,
                                              const float* __restrict__ dinv, const float* __restrict__ bo,
                                              int n) {
  int tid = blockIdx.x * 256 + threadIdx.x;
  int q = tid >> 4, lane = tid & 15;
  if (q >= n) return;
  int beg = rowptr[q], end = rowptr[q + 1];
  float acc = 0.f;
  for (int p = beg + lane; p < end; p += 16) acc += t5[__builtin_nontemporal_load(&csr[p])];
#pragma unroll
  for (int off = 1; off < 16; off <<= 1) acc += __shfl_xor(acc, off);
  if (lane == 0) probs[q] = fmaf(dinv[q], acc, bo[0]);
}

// ---------------- t5' = h4' @ Wo (stays pre-scaled), mean un-scales ----------------
__global__ __launch_bounds__(256) void k_t5mean(const int4* __restrict__ tA, const int* __restrict__ tB,
                                                const float* __restrict__ Wo, const float* __restrict__ dinv,
                                                float* __restrict__ t5, float* __restrict__ part, int n) {
  int tid = blockIdx.x * 256 + threadIdx.x;
  float wo[10];
#pragma unroll
  for (int k = 0; k < 10; ++k) wo[k] = Wo[k];
  float p[10];
#pragma unroll
  for (int k = 0; k < 10; ++k) p[k] = 0.f;
  for (int rowi = tid; rowi < n; rowi += 128 * 256) {
    int4 a = tA[rowi];
    int b = tB[rowi];
    float2 f0 = h2f(a.x), f1 = h2f(a.y), f2 = h2f(a.z), f3 = h2f(a.w), f4 = h2f(b);
    float hv[10] = {f0.x, f0.y, f1.x, f1.y, f2.x, f2.y, f3.x, f3.y, f4.x, f4.y};
    float s = 0.f;
#pragma unroll
    for (int k = 0; k < 10; ++k) s = fmaf(hv[k], wo[k], s);
    t5[rowi] = s;
    float inv = 1.0f / dinv[rowi];  // un-scale for the mean
#pragma unroll
    for (int k = 0; k < 10; ++k) p[k] = fmaf(hv[k], inv, p[k]);
  }
#pragma unroll
  for (int off = 1; off < 64; off <<= 1)
#pragma unroll
    for (int k = 0; k < 10; ++k) p[k] += __shfl_xor(p[k], off);
  __shared__ float sp[4][10];
  int w = threadIdx.x >> 6, ln = threadIdx.x & 63;
  if (ln == 0) {
#pragma unroll
    for (int k = 0; k < 10; ++k) sp[w][k] = p[k];
  }
  __syncthreads();
  if (threadIdx.x < 10)
    part[blockIdx.x * 10 + threadIdx.x] =
        sp[0][threadIdx.x] + sp[1][threadIdx.x] + sp[2][threadIdx.x] + sp[3][threadIdx.x];
}

__global__ void k_finish(const float* __restrict__ part, const float* __restrict__ Wdn,
                         const float* __restrict__ bdn, const float* __restrict__ Wv,
                         const float* __restrict__ bv, float* __restrict__ out, int n, int nPart) {
  __shared__ float m[10];
  int t = threadIdx.x;
  if (t < 10) {
    float s = 0.f;
    for (int b = 0; b < nPart; ++b) s += part[b * 10 + t];
    m[t] = s / (float)n;
  }
  __syncthreads();
  if (t == 0) {
    float pn = bdn[0], vv = bv[0];
    for (int k = 0; k < 10; ++k) {
      pn = fmaf(m[k], Wdn[k], pn);
      vv = fmaf(m[k], Wv[k], vv);
    }
    out[n] = pn;
    out[n + 1] = vv;
  }
}

extern "C" void kernel_launch(void* const* d_in, const int* in_sizes, int n_in,
                              void* d_out, int out_size, void* d_ws, size_t ws_size,
                              hipStream_t stream) {
  const float* x  = (const float*)d_in[0];
  const int* ei   = (const int*)d_in[1];
  const float* W1 = (const float*)d_in[2];
  const float* b1 = (const float*)d_in[3];
  const float* W2 = (const float*)d_in[4];
  const float* b2 = (const float*)d_in[5];
  const float* Wp = (const float*)d_in[6];
  const float* bp = (const float*)d_in[7];
  const float* W3 = (const float*)d_in[8];
  const float* b3 = (const float*)d_in[9];
  const float* Wo = (const float*)d_in[10];
  const float* bo = (const float*)d_in[11];
  const float* Wdn = (const float*)d_in[12];
  const float* bdn = (const float*)d_in[13];
  const float* Wv = (const float*)d_in[14];
  const float* bv = (const float*)d_in[15];

  int N = in_sizes[0] / 128;
  int E = in_sizes[1] / 2;
  const int* row = ei;
  const int* colv = ei + E;
  float* out = (float*)d_out;
  int nbuck = (N + NPB - 1) >> BSH;            // <= 512
  int bb = (E + BIN_CHUNK - 1) / BIN_CHUNK;
  size_t M = (size_t)nbuck * bb;

  char* ws = (char*)d_ws;
  size_t off = 0;
  auto alloc = [&](size_t b) -> void* {
    void* p = ws + off;
    off += (b + 255) & ~(size_t)255;
    return p;
  };
  int* csr_r = (int*)alloc((size_t)(E + N) * 4);
  int* csr_c = (int*)alloc((size_t)(E + N) * 4);
  int* rp_r = (int*)alloc((size_t)(N + 1) * 4);
  int* rp_c = (int*)alloc((size_t)(N + 1) * 4);
  float* dinv_r = (float*)alloc((size_t)N * 4);
  float* dinv_c = (float*)alloc((size_t)N * 4);
  int* hist = (int*)alloc((M + 1) * 4);
  int* bsum = (int*)alloc(4096);
  // union region: bin (build phase) overlaps split hidden-state arrays (compute phase)
  size_t binB = (size_t)E * 4;
  size_t tB_ = (size_t)N * 44 + 8192;
  char* region = (char*)alloc(binB > tB_ ? binB : tB_);
  int* bin = (int*)region;
  int4* tA_a = (int4*)region;                               // 16N
  int*  tB_a = (int*)(region + (size_t)N * 16);             // 4N
  int4* tA_b = (int4*)(region + (size_t)N * 20);            // 16N
  int*  tB_b = (int*)(region + (size_t)N * 36);             // 4N
  float* t5  = (float*)(region + (size_t)N * 40);           // 4N
  float* part = (float*)(region + (size_t)N * 44);
  if (off > ws_size) {
    fprintf(stderr, "WS too small: need %zu have %zu\n", off, ws_size);
    return;
  }

  int sb2 = (int)((M + 2047) / 2048);
  int ab = (int)(((size_t)N * 16 + 255) / 256);

  // build row-CSR (dst=row, src=col)
  k_histpb<<<bb, 256, 0, stream>>>(row, hist, E, bb, nbuck);
  k_scanA<<<sb2, 256, 0, stream>>>(hist, hist, bsum, (int)M);
  k_scanB<<<1, 1024, 0, stream>>>(bsum, sb2);
  k_scanC<<<sb2, 256, 0, stream>>>(hist, bsum, (int)M, E);
  k_binR<<<bb, 512, 0, stream>>>(row, colv, hist, bin, E, bb, nbuck);
  k_buildcsr<<<nbuck, 1024, 0, stream>>>(bin, hist, rp_r, csr_r, dinv_r, N, E, bb);
  // build col-CSR (dst=col, src=row)
  k_histpb<<<bb, 256, 0, stream>>>(colv, hist, E, bb, nbuck);
  k_scanA<<<sb2, 256, 0, stream>>>(hist, hist, bsum, (int)M);
  k_scanB<<<1, 1024, 0, stream>>>(bsum, sb2);
  k_scanC<<<sb2, 256, 0, stream>>>(hist, bsum, (int)M, E);
  k_binR<<<bb, 512, 0, stream>>>(colv, row, hist, bin, E, bb, nbuck);
  k_buildcsr<<<nbuck, 1024, 0, stream>>>(bin, hist, rp_c, csr_c, dinv_c, N, E, bb);

  // network (hidden rows split fp16, pre-scaled by the NEXT consumer's dinv)
  k_xw<<<2048, 256, 0, stream>>>(x, W1, dinv_r, tA_a, tB_a, N);
  k_agg10<false><<<ab, 256, 0, stream>>>(tA_a, tB_a, (__half*)tA_b, (__half*)tB_b,
                                         csr_r, rp_r, dinv_r, dinv_r, nullptr, b1, N);
  k_agg10<true><<<ab, 256, 0, stream>>>(tA_b, tB_b, (__half*)tA_a, (__half*)tB_a,
                                        csr_r, rp_r, dinv_r, dinv_c, W2, b2, N);
  k_agg10<true><<<ab, 256, 0, stream>>>(tA_a, tB_a, (__half*)tA_b, (__half*)tB_b,
                                        csr_c, rp_c, dinv_c, dinv_r, Wp, bp, N);
  k_agg10<true><<<ab, 256, 0, stream>>>(tA_b, tB_b, (__half*)tA_a, (__half*)tB_a,
                                        csr_r, rp_r, dinv_r, dinv_r, W3, b3, N);
  k_t5mean<<<128, 256, 0, stream>>>(tA_a, tB_a, Wo, dinv_r, t5, part, N);
  k_agg1<<<ab, 256, 0, stream>>>(t5, out, csr_r, rp_r, dinv_r, bo, N);
  k_finish<<<1, 64, 0, stream>>>(part, Wdn, bdn, Wv, bv, out, N, 128);
}

// Round 10
// 478.047 us; speedup vs baseline: 1.2368x; 1.2368x over previous
//
#include <hip/hip_runtime.h>
#include <hip/hip_fp16.h>
#include <cstdio>

constexpr int NPB = 512;      // nodes per bucket (power of 2)
constexpr int BSH = 9;        // log2(NPB)
constexpr int BIN_CHUNK = 8192;  // edges per block in binning passes (LDS reorder buffer)
constexpr int CAP = 18432;    // LDS staging entries in buildcsr (72KB)

// ---- block-fp row codec: 10 dims -> 16B (10x12-bit signed mantissa + shared exp) ----
// layout: dword j holds dims 2j (bits 0-11), 2j+1 (bits 16-27) for j=0..3 (dims 0-7).
// spare nibbles (bits 12-15, 28-31 of each dword) hold dims 8,9 (12b each) + exp (8b).
__device__ __forceinline__ int4 pack10(const float o[10]) {
  float mx = fabsf(o[0]);
#pragma unroll
  for (int k = 1; k < 10; ++k) mx = fmaxf(mx, fabsf(o[k]));
  int4 r;
  if (mx < 1e-30f) { r.x = 0; r.y = 0; r.z = 0; r.w = 0; return r; }
  int ebits = (__float_as_int(mx) >> 23) & 0xFF;
  if (ebits < 11) ebits = 11;
  float senc = __int_as_float((264 - ebits) << 23);  // 2^(10-E)
  int m[10];
#pragma unroll
  for (int k = 0; k < 10; ++k) {
    int v = (int)rintf(o[k] * senc);
    m[k] = min(2047, max(-2047, v));
  }
  int u8 = m[8] & 0xFFF, u9 = m[9] & 0xFFF;
  int e8 = ebits - 10;  // decode scale = 2^(E-10) = as_float(e8<<23)
  r.x = (m[0] & 0xFFF) | ((m[1] & 0xFFF) << 16) | ((u8 & 0xF) << 12) | (((u8 >> 4) & 0xF) << 28);
  r.y = (m[2] & 0xFFF) | ((m[3] & 0xFFF) << 16) | (((u8 >> 8) & 0xF) << 12) | ((u9 & 0xF) << 28);
  r.z = (m[4] & 0xFFF) | ((m[5] & 0xFFF) << 16) | (((u9 >> 4) & 0xF) << 12) | (((u9 >> 8) & 0xF) << 28);
  r.w = (m[6] & 0xFFF) | ((m[7] & 0xFFF) << 16) | ((e8 & 0xF) << 12) | (((e8 >> 4) & 0xF) << 28);
  return r;
}

__device__ __forceinline__ void unpack10_acc(int4 v, float acc[10]) {
  int e8 = ((v.w >> 12) & 0xF) | (((v.w >> 28) & 0xF) << 4);
  float s = __int_as_float(e8 << 23);
  int d[4] = {v.x, v.y, v.z, v.w};
#pragma unroll
  for (int j = 0; j < 4; ++j) {
    int lo = (d[j] << 20) >> 20;
    int hi = (d[j] << 4) >> 20;
    acc[2 * j] = fmaf((float)lo, s, acc[2 * j]);
    acc[2 * j + 1] = fmaf((float)hi, s, acc[2 * j + 1]);
  }
  int m8 = ((v.x >> 12) & 0xF) | (((v.x >> 28) & 0xF) << 4) | (((v.y >> 12) & 0xF) << 8);
  m8 = (m8 << 20) >> 20;
  int m9 = ((v.y >> 28) & 0xF) | (((v.z >> 12) & 0xF) << 4) | (((v.z >> 28) & 0xF) << 8);
  m9 = (m9 << 20) >> 20;
  acc[8] = fmaf((float)m8, s, acc[8]);
  acc[9] = fmaf((float)m9, s, acc[9]);
}

__device__ __forceinline__ void unpack10(int4 v, float o[10]) {
#pragma unroll
  for (int k = 0; k < 10; ++k) o[k] = 0.f;
  unpack10_acc(v, o);
}

// ---------------- bucketed CSR build (zero per-edge global atomics, coalesced shuffle) -------

__global__ __launch_bounds__(256) void k_histpb(const int* __restrict__ dst, int* __restrict__ hist,
                                                int E, int nblocks, int nbuck) {
  __shared__ int h[512];
  int t = threadIdx.x;
  h[t] = 0;
  h[t + 256] = 0;
  __syncthreads();
  int e0 = blockIdx.x * BIN_CHUNK + t;
  int eend = min(E, (blockIdx.x + 1) * BIN_CHUNK);
  for (int e = e0; e < eend; e += 256) atomicAdd(&h[dst[e] >> BSH], 1);
  __syncthreads();
  for (int b = t; b < nbuck; b += 256) hist[(size_t)b * nblocks + blockIdx.x] = h[b];
}

__global__ __launch_bounds__(256) void k_scanA(const int* __restrict__ in, int* __restrict__ out,
                                               int* __restrict__ bsum, int n) {
  int base = blockIdx.x * 2048 + threadIdx.x * 8;
  int v[8];
  int run = 0;
#pragma unroll
  for (int i = 0; i < 8; ++i) { int idx = base + i; v[i] = (idx < n) ? in[idx] : 0; }
#pragma unroll
  for (int i = 0; i < 8; ++i) { int t = v[i]; v[i] = run; run += t; }
  __shared__ int s[256];
  s[threadIdx.x] = run;
  __syncthreads();
  for (int off = 1; off < 256; off <<= 1) {
    int t = (threadIdx.x >= off) ? s[threadIdx.x - off] : 0;
    __syncthreads();
    s[threadIdx.x] += t;
    __syncthreads();
  }
  int toff = s[threadIdx.x] - run;
#pragma unroll
  for (int i = 0; i < 8; ++i) { int idx = base + i; if (idx < n) out[idx] = v[i] + toff; }
  if (threadIdx.x == 255) bsum[blockIdx.x] = s[255];
}

__global__ __launch_bounds__(1024) void k_scanB(int* bsum, int nb) {
  __shared__ int s[1024];
  int t = threadIdx.x;
  int v = (t < nb) ? bsum[t] : 0;
  s[t] = v;
  __syncthreads();
  for (int off = 1; off < 1024; off <<= 1) {
    int tv = (t >= off) ? s[t - off] : 0;
    __syncthreads();
    s[t] += tv;
    __syncthreads();
  }
  if (t < nb) bsum[t] = s[t] - v;  // exclusive
}

__global__ __launch_bounds__(256) void k_scanC(int* __restrict__ out, const int* __restrict__ bsum,
                                               int n, int total) {
  int base = blockIdx.x * 2048 + threadIdx.x * 8;
  int add = bsum[blockIdx.x];
#pragma unroll
  for (int i = 0; i < 8; ++i) { int idx = base + i; if (idx < n) out[idx] += add; }
  if (blockIdx.x == 0 && threadIdx.x == 0) out[n] = total;
}

// Pass 2: reorder chunk in LDS (bucket-major), then all-lane coalesced write-out via
// 9-step binary search. 512 threads, 38KB LDS -> 4 blocks/CU.
__global__ __launch_bounds__(512) void k_binR(const int* __restrict__ dst, const int* __restrict__ src,
                                              const int* __restrict__ hist_s, int* __restrict__ bin,
                                              int E, int nblocks, int nbuck) {
  __shared__ int lbuf[BIN_CHUNK];
  __shared__ int ls[512];
  __shared__ int cur[512];
  __shared__ int gbase[512];
  int t = threadIdx.x;
  cur[t] = 0;
  __syncthreads();
  int blk0 = blockIdx.x * BIN_CHUNK;
  int eend = min(E, blk0 + BIN_CHUNK);
  int nent = eend - blk0;
  for (int e = blk0 + t; e < eend; e += 512) atomicAdd(&cur[dst[e] >> BSH], 1);
  __syncthreads();
  int v = cur[t];
  ls[t] = v;
  __syncthreads();
  for (int off = 1; off < 512; off <<= 1) {
    int x = (t >= off) ? ls[t - off] : 0;
    __syncthreads();
    ls[t] += x;
    __syncthreads();
  }
  int excl = ls[t] - v;
  __syncthreads();
  ls[t] = excl;
  cur[t] = excl;
  gbase[t] = (t < nbuck) ? hist_s[(size_t)t * nblocks + blockIdx.x] : 0;
  __syncthreads();
  for (int e = blk0 + t; e < eend; e += 512) {
    int d = dst[e];
    int slot = atomicAdd(&cur[d >> BSH], 1);
    lbuf[slot] = ((d & (NPB - 1)) << 18) | src[e];
  }
  __syncthreads();
  for (int i = t; i < nent; i += 512) {
    int w = lbuf[i];
    int lo = 0;
#pragma unroll
    for (int sh = 256; sh > 0; sh >>= 1) {
      int mid = lo + sh;
      if (mid < 512 && ls[mid] <= i) lo = mid;
    }
    __builtin_nontemporal_store(w, &bin[gbase[lo] + (i - ls[lo])]);
  }
}

// Pass 3: one 1024-thread WG per 512-node bucket. Single count pass + single LDS scatter
// + coalesced dump. 76KB LDS -> 2 blocks/CU.
__global__ __launch_bounds__(1024) void k_buildcsr(const int* __restrict__ bin, const int* __restrict__ hist_s,
                                                   int* __restrict__ rowptr, int* __restrict__ csr,
                                                   float* __restrict__ dinv, int N, int Etot, int nblocks) {
  __shared__ int cnt[NPB];
  __shared__ int sc[NPB];
  __shared__ int lbuf[CAP];
  int t = threadIdx.x;
  int b = blockIdx.x;
  int node0 = b << BSH;
  int nn = min(NPB, N - node0);
  int ebeg = hist_s[(size_t)b * nblocks];
  int eend = hist_s[(size_t)(b + 1) * nblocks];
  if (t < NPB) cnt[t] = (t < nn) ? 1 : 0;  // self loop
  __syncthreads();
  for (int p = ebeg + t; p < eend; p += 1024)
    atomicAdd(&cnt[__builtin_nontemporal_load(&bin[p]) >> 18], 1);
  __syncthreads();
  int v = 0;
  if (t < NPB) { v = cnt[t]; sc[t] = v; }
  __syncthreads();
  for (int off = 1; off < NPB; off <<= 1) {
    int x = (t >= off && t < NPB) ? sc[t - off] : 0;
    __syncthreads();
    if (t < NPB) sc[t] += x;
    __syncthreads();
  }
  int excl = (t < NPB) ? (sc[t] - v) : 0;
  int cbase = ebeg + node0;
  if (t < nn) {
    rowptr[node0 + t] = cbase + excl;
    dinv[node0 + t] = rsqrtf((float)v);
  }
  int total2 = (eend - ebeg) + nn;
  bool stage = (total2 <= CAP);
  __syncthreads();
  if (t < NPB) cnt[t] = excl + ((t < nn) ? 1 : 0);
  if (t < nn) {
    if (stage) lbuf[excl] = node0 + t;
    else       csr[cbase + excl] = node0 + t;
  }
  __syncthreads();
  for (int p = ebeg + t; p < eend; p += 1024) {
    int w = __builtin_nontemporal_load(&bin[p]);
    int slot = atomicAdd(&cnt[w >> 18], 1);
    if (stage) lbuf[slot] = w & 0x3FFFF;
    else       csr[cbase + slot] = w & 0x3FFFF;
  }
  __syncthreads();
  if (stage)
    for (int i = t; i < total2; i += 1024)
      __builtin_nontemporal_store(lbuf[i], &csr[cbase + i]);
  if (b == 0 && t == 0) rowptr[N] = Etot + N;
}

// ---------------- x @ W1 -> packed block-fp rows (pre-scaled by dinv_r) ----------------
__global__ __launch_bounds__(256) void k_xw(const float* __restrict__ x, const float* __restrict__ W1,
                                            const float* __restrict__ dinv, int4* __restrict__ tA, int n) {
  int tid = blockIdx.x * 256 + threadIdx.x;
  int sub = tid & 15;
  int rowStart = tid >> 4;
  int rowStride = (gridDim.x * 256) >> 4;
  float w[8][10];
#pragma unroll
  for (int jj = 0; jj < 8; ++jj)
#pragma unroll
    for (int k = 0; k < 10; ++k) w[jj][k] = W1[(sub * 8 + jj) * 10 + k];
  for (int row = rowStart; row < n; row += rowStride) {
    const float* xr = x + (size_t)row * 128 + sub * 8;
    float4 a = *(const float4*)xr;
    float4 b = *(const float4*)(xr + 4);
    float xv[8] = {a.x, a.y, a.z, a.w, b.x, b.y, b.z, b.w};
    float acc[10];
#pragma unroll
    for (int k = 0; k < 10; ++k) acc[k] = 0.f;
#pragma unroll
    for (int jj = 0; jj < 8; ++jj)
#pragma unroll
      for (int k = 0; k < 10; ++k) acc[k] = fmaf(xv[jj], w[jj][k], acc[k]);
#pragma unroll
    for (int off = 1; off < 16; off <<= 1)
#pragma unroll
      for (int k = 0; k < 10; ++k) acc[k] += __shfl_xor(acc[k], off);
    if (sub == 0) {
      float d = dinv[row];
      float o[10];
#pragma unroll
      for (int k = 0; k < 10; ++k) o[k] = acc[k] * d;
      tA[row] = pack10(o);
    }
  }
}

// ---------------- fused GCN layer (block-fp rows, pre-scaled; 1 request/edge) ----------------
template <bool USE_W>
__global__ __launch_bounds__(256) void k_agg10(const int4* __restrict__ tin, int4* __restrict__ tout,
                                               const int* __restrict__ csr, const int* __restrict__ rowptr,
                                               const float* __restrict__ dinv_d, const float* __restrict__ dnext,
                                               const float* __restrict__ W, const float* __restrict__ bias,
                                               int n) {
  int tid = blockIdx.x * 256 + threadIdx.x;
  int q = tid >> 4, lane = tid & 15;
  if (q >= n) return;
  int beg = rowptr[q], end = rowptr[q + 1];
  float acc[10];
#pragma unroll
  for (int k = 0; k < 10; ++k) acc[k] = 0.f;
  for (int p = beg + lane; p < end; p += 16) {
    int src = __builtin_nontemporal_load(&csr[p]);
    int4 a = tin[src];
    unpack10_acc(a, acc);
  }
#pragma unroll
  for (int off = 1; off < 16; off <<= 1)
#pragma unroll
    for (int k = 0; k < 10; ++k) acc[k] += __shfl_xor(acc[k], off);
  float o = 0.f;
  if (lane < 10) {
    float dd = dinv_d[q];
    float dn = dnext[q];
    o = bias[lane];
    if (USE_W) {
#pragma unroll
      for (int m = 0; m < 10; ++m) o = fmaf(acc[m] * dd, W[m * 10 + lane], o);
    } else {
      o += acc[lane] * dd;
    }
    o = fmaxf(o, 0.f) * dn;
  }
  // gather the quarter's 10 outputs to its lane 0, pack, one 16B store
  int l = threadIdx.x & 63;
  int qbase = l & 48;
  float oj[10];
#pragma unroll
  for (int k = 0; k < 10; ++k) oj[k] = __shfl(o, qbase + k, 64);
  if (lane == 0) tout[q] = pack10(oj);
}

// ---------------- output layer: probs[q] = dd * sum t5'[src] + bo  (t5' pre-scaled) ----------
__global__ __launch_bounds__(256) void k_agg1(const float* __restrict__ t5, float* __restrict__ probs,
                                              const int* __restrict__ csr, const int* __restrict__ rowptr,
                                              const float* __restrict__ dinv, const float* __restrict__ bo,
                                              int n) {
  int tid = blockIdx.x * 256 + threadIdx.x;
  int q = tid >> 4, lane = tid & 15;
  if (q >= n) return;
  int beg = rowptr[q], end = rowptr[q + 1];
  float acc = 0.f;
  for (int p = beg + lane; p < end; p += 16) acc += t5[__builtin_nontemporal_load(&csr[p])];
#pragma unroll
  for (int off = 1; off < 16; off <<= 1) acc += __shfl_xor(acc, off);
  if (lane == 0) probs[q] = fmaf(dinv[q], acc, bo[0]);
}

// ---------------- t5' = h4' @ Wo (stays pre-scaled), mean un-scales ----------------
__global__ __launch_bounds__(256) void k_t5mean(const int4* __restrict__ tA, const float* __restrict__ Wo,
                                                const float* __restrict__ dinv, float* __restrict__ t5,
                                                float* __restrict__ part, int n) {
  int tid = blockIdx.x * 256 + threadIdx.x;
  float wo[10];
#pragma unroll
  for (int k = 0; k < 10; ++k) wo[k] = Wo[k];
  float p[10];
#pragma unroll
  for (int k = 0; k < 10; ++k) p[k] = 0.f;
  for (int rowi = tid; rowi < n; rowi += 128 * 256) {
    int4 a = tA[rowi];
    float hv[10];
    unpack10(a, hv);
    float s = 0.f;
#pragma unroll
    for (int k = 0; k < 10; ++k) s = fmaf(hv[k], wo[k], s);
    t5[rowi] = s;
    float inv = 1.0f / dinv[rowi];  // un-scale for the mean
#pragma unroll
    for (int k = 0; k < 10; ++k) p[k] = fmaf(hv[k], inv, p[k]);
  }
#pragma unroll
  for (int off = 1; off < 64; off <<= 1)
#pragma unroll
    for (int k = 0; k < 10; ++k) p[k] += __shfl_xor(p[k], off);
  __shared__ float sp[4][10];
  int w = threadIdx.x >> 6, ln = threadIdx.x & 63;
  if (ln == 0) {
#pragma unroll
    for (int k = 0; k < 10; ++k) sp[w][k] = p[k];
  }
  __syncthreads();
  if (threadIdx.x < 10)
    part[blockIdx.x * 10 + threadIdx.x] =
        sp[0][threadIdx.x] + sp[1][threadIdx.x] + sp[2][threadIdx.x] + sp[3][threadIdx.x];
}

__global__ void k_finish(const float* __restrict__ part, const float* __restrict__ Wdn,
                         const float* __restrict__ bdn, const float* __restrict__ Wv,
                         const float* __restrict__ bv, float* __restrict__ out, int n, int nPart) {
  __shared__ float m[10];
  int t = threadIdx.x;
  if (t < 10) {
    float s = 0.f;
    for (int b = 0; b < nPart; ++b) s += part[b * 10 + t];
    m[t] = s / (float)n;
  }
  __syncthreads();
  if (t == 0) {
    float pn = bdn[0], vv = bv[0];
    for (int k = 0; k < 10; ++k) {
      pn = fmaf(m[k], Wdn[k], pn);
      vv = fmaf(m[k], Wv[k], vv);
    }
    out[n] = pn;
    out[n + 1] = vv;
  }
}

extern "C" void kernel_launch(void* const* d_in, const int* in_sizes, int n_in,
                              void* d_out, int out_size, void* d_ws, size_t ws_size,
                              hipStream_t stream) {
  const float* x  = (const float*)d_in[0];
  const int* ei   = (const int*)d_in[1];
  const float* W1 = (const float*)d_in[2];
  const float* b1 = (const float*)d_in[3];
  const float* W2 = (const float*)d_in[4];
  const float* b2 = (const float*)d_in[5];
  const float* Wp = (const float*)d_in[6];
  const float* bp = (const float*)d_in[7];
  const float* W3 = (const float*)d_in[8];
  const float* b3 = (const float*)d_in[9];
  const float* Wo = (const float*)d_in[10];
  const float* bo = (const float*)d_in[11];
  const float* Wdn = (const float*)d_in[12];
  const float* bdn = (const float*)d_in[13];
  const float* Wv = (const float*)d_in[14];
  const float* bv = (const float*)d_in[15];

  int N = in_sizes[0] / 128;
  int E = in_sizes[1] / 2;
  const int* row = ei;
  const int* colv = ei + E;
  float* out = (float*)d_out;
  int nbuck = (N + NPB - 1) >> BSH;
  int bb = (E + BIN_CHUNK - 1) / BIN_CHUNK;
  size_t M = (size_t)nbuck * bb;

  char* ws = (char*)d_ws;
  size_t off = 0;
  auto alloc = [&](size_t b) -> void* {
    void* p = ws + off;
    off += (b + 255) & ~(size_t)255;
    return p;
  };
  int* csr_r = (int*)alloc((size_t)(E + N) * 4);
  int* csr_c = (int*)alloc((size_t)(E + N) * 4);
  int* rp_r = (int*)alloc((size_t)(N + 1) * 4);
  int* rp_c = (int*)alloc((size_t)(N + 1) * 4);
  float* dinv_r = (float*)alloc((size_t)N * 4);
  float* dinv_c = (float*)alloc((size_t)N * 4);
  int* hist = (int*)alloc((M + 1) * 4);
  int* bsum = (int*)alloc(4096);
  // union region: bin (build phase) overlaps packed hidden-state arrays (compute phase)
  size_t binB = (size_t)E * 4;
  size_t tB_ = (size_t)N * 36 + 8192;   // tA_a 16N + tA_b 16N + t5 4N + part
  char* region = (char*)alloc(binB > tB_ ? binB : tB_);
  int* bin = (int*)region;
  int4* tA_a = (int4*)region;                               // 16N
  int4* tA_b = (int4*)(region + (size_t)N * 16);            // 16N
  float* t5  = (float*)(region + (size_t)N * 32);           // 4N
  float* part = (float*)(region + (size_t)N * 36);
  if (off > ws_size) {
    fprintf(stderr, "WS too small: need %zu have %zu\n", off, ws_size);
    return;
  }

  int sb2 = (int)((M + 2047) / 2048);
  int ab = (int)(((size_t)N * 16 + 255) / 256);

  // build row-CSR (dst=row, src=col)
  k_histpb<<<bb, 256, 0, stream>>>(row, hist, E, bb, nbuck);
  k_scanA<<<sb2, 256, 0, stream>>>(hist, hist, bsum, (int)M);
  k_scanB<<<1, 1024, 0, stream>>>(bsum, sb2);
  k_scanC<<<sb2, 256, 0, stream>>>(hist, bsum, (int)M, E);
  k_binR<<<bb, 512, 0, stream>>>(row, colv, hist, bin, E, bb, nbuck);
  k_buildcsr<<<nbuck, 1024, 0, stream>>>(bin, hist, rp_r, csr_r, dinv_r, N, E, bb);
  // build col-CSR (dst=col, src=row)
  k_histpb<<<bb, 256, 0, stream>>>(colv, hist, E, bb, nbuck);
  k_scanA<<<sb2, 256, 0, stream>>>(hist, hist, bsum, (int)M);
  k_scanB<<<1, 1024, 0, stream>>>(bsum, sb2);
  k_scanC<<<sb2, 256, 0, stream>>>(hist, bsum, (int)M, E);
  k_binR<<<bb, 512, 0, stream>>>(colv, row, hist, bin, E, bb, nbuck);
  k_buildcsr<<<nbuck, 1024, 0, stream>>>(bin, hist, rp_c, csr_c, dinv_c, N, E, bb);

  // network (hidden rows packed block-fp 16B, pre-scaled by the NEXT consumer's dinv)
  k_xw<<<2048, 256, 0, stream>>>(x, W1, dinv_r, tA_a, N);
  k_agg10<false><<<ab, 256, 0, stream>>>(tA_a, tA_b, csr_r, rp_r, dinv_r, dinv_r, nullptr, b1, N);
  k_agg10<true><<<ab, 256, 0, stream>>>(tA_b, tA_a, csr_r, rp_r, dinv_r, dinv_c, W2, b2, N);
  k_agg10<true><<<ab, 256, 0, stream>>>(tA_a, tA_b, csr_c, rp_c, dinv_c, dinv_r, Wp, bp, N);
  k_agg10<true><<<ab, 256, 0, stream>>>(tA_b, tA_a, csr_r, rp_r, dinv_r, dinv_r, W3, b3, N);
  k_t5mean<<<128, 256, 0, stream>>>(tA_a, Wo, dinv_r, t5, part, N);
  k_agg1<<<ab, 256, 0, stream>>>(t5, out, csr_r, rp_r, dinv_r, bo, N);
  k_finish<<<1, 64, 0, stream>>>(part, Wdn, bdn, Wv, bv, out, N, 128);
}

// Round 11
// 383.108 us; speedup vs baseline: 1.5433x; 1.2478x over previous
//
#include <hip/hip_runtime.h>
#include <hip/hip_fp16.h>
#include <cstdio>

constexpr int NPB = 512;      // nodes per bucket (power of 2)
constexpr int BSH = 9;        // log2(NPB)
constexpr int BIN_CHUNK = 16384; // edges per block in binning passes (LDS reorder buffer)
constexpr int CAP = 18432;    // LDS staging entries in buildcsr (72KB)

// ---- block-fp row codec: 10 dims -> 16B (10x12-bit signed mantissa + shared exp) ----
__device__ __forceinline__ int4 pack10(const float o[10]) {
  float mx = fabsf(o[0]);
#pragma unroll
  for (int k = 1; k < 10; ++k) mx = fmaxf(mx, fabsf(o[k]));
  int4 r;
  if (mx < 1e-30f) { r.x = 0; r.y = 0; r.z = 0; r.w = 0; return r; }
  int ebits = (__float_as_int(mx) >> 23) & 0xFF;
  if (ebits < 11) ebits = 11;
  float senc = __int_as_float((264 - ebits) << 23);  // 2^(10-E)
  int m[10];
#pragma unroll
  for (int k = 0; k < 10; ++k) {
    int v = (int)rintf(o[k] * senc);
    m[k] = min(2047, max(-2047, v));
  }
  int u8 = m[8] & 0xFFF, u9 = m[9] & 0xFFF;
  int e8 = ebits - 10;  // decode scale = 2^(E-10) = as_float(e8<<23)
  r.x = (m[0] & 0xFFF) | ((m[1] & 0xFFF) << 16) | ((u8 & 0xF) << 12) | (((u8 >> 4) & 0xF) << 28);
  r.y = (m[2] & 0xFFF) | ((m[3] & 0xFFF) << 16) | (((u8 >> 8) & 0xF) << 12) | ((u9 & 0xF) << 28);
  r.z = (m[4] & 0xFFF) | ((m[5] & 0xFFF) << 16) | (((u9 >> 4) & 0xF) << 12) | (((u9 >> 8) & 0xF) << 28);
  r.w = (m[6] & 0xFFF) | ((m[7] & 0xFFF) << 16) | ((e8 & 0xF) << 12) | (((e8 >> 4) & 0xF) << 28);
  return r;
}

__device__ __forceinline__ void unpack10_acc(int4 v, float acc[10]) {
  int e8 = ((v.w >> 12) & 0xF) | (((v.w >> 28) & 0xF) << 4);
  float s = __int_as_float(e8 << 23);
  int d[4] = {v.x, v.y, v.z, v.w};
#pragma unroll
  for (int j = 0; j < 4; ++j) {
    int lo = (d[j] << 20) >> 20;
    int hi = (d[j] << 4) >> 20;
    acc[2 * j] = fmaf((float)lo, s, acc[2 * j]);
    acc[2 * j + 1] = fmaf((float)hi, s, acc[2 * j + 1]);
  }
  int m8 = ((v.x >> 12) & 0xF) | (((v.x >> 28) & 0xF) << 4) | (((v.y >> 12) & 0xF) << 8);
  m8 = (m8 << 20) >> 20;
  int m9 = ((v.y >> 28) & 0xF) | (((v.z >> 12) & 0xF) << 4) | (((v.z >> 28) & 0xF) << 8);
  m9 = (m9 << 20) >> 20;
  acc[8] = fmaf((float)m8, s, acc[8]);
  acc[9] = fmaf((float)m9, s, acc[9]);
}

__device__ __forceinline__ void unpack10(int4 v, float o[10]) {
#pragma unroll
  for (int k = 0; k < 10; ++k) o[k] = 0.f;
  unpack10_acc(v, o);
}

// ---------------- bucketed CSR build ----------------

// fused per-chunk histograms for BOTH directions: hist[b*nblocks+blk] (row),
// hist[M + b*nblocks+blk] (col)
__global__ __launch_bounds__(1024) void k_histpb2(const int* __restrict__ rowv, const int* __restrict__ colv,
                                                  int* __restrict__ hist, int E, int nblocks, int nbuck, int M) {
  __shared__ int hr[512], hc[512];
  int t = threadIdx.x;
  if (t < 512) { hr[t] = 0; hc[t] = 0; }
  __syncthreads();
  int blk0 = blockIdx.x * BIN_CHUNK;
  int eend = min(E, blk0 + BIN_CHUNK);
  for (int e = blk0 + t; e < eend; e += 1024) {
    atomicAdd(&hr[rowv[e] >> BSH], 1);
    atomicAdd(&hc[colv[e] >> BSH], 1);
  }
  __syncthreads();
  if (t < nbuck) {
    hist[(size_t)t * nblocks + blockIdx.x] = hr[t];
    hist[M + (size_t)t * nblocks + blockIdx.x] = hc[t];
  }
}

__global__ __launch_bounds__(256) void k_scanA(const int* __restrict__ in, int* __restrict__ out,
                                               int* __restrict__ bsum, int n) {
  int base = blockIdx.x * 2048 + threadIdx.x * 8;
  int v[8];
  int run = 0;
#pragma unroll
  for (int i = 0; i < 8; ++i) { int idx = base + i; v[i] = (idx < n) ? in[idx] : 0; }
#pragma unroll
  for (int i = 0; i < 8; ++i) { int t = v[i]; v[i] = run; run += t; }
  __shared__ int s[256];
  s[threadIdx.x] = run;
  __syncthreads();
  for (int off = 1; off < 256; off <<= 1) {
    int t = (threadIdx.x >= off) ? s[threadIdx.x - off] : 0;
    __syncthreads();
    s[threadIdx.x] += t;
    __syncthreads();
  }
  int toff = s[threadIdx.x] - run;
#pragma unroll
  for (int i = 0; i < 8; ++i) { int idx = base + i; if (idx < n) out[idx] = v[i] + toff; }
  if (threadIdx.x == 255) bsum[blockIdx.x] = s[255];
}

__global__ __launch_bounds__(1024) void k_scanB(int* bsum, int nb) {
  __shared__ int s[1024];
  int t = threadIdx.x;
  int v = (t < nb) ? bsum[t] : 0;
  s[t] = v;
  __syncthreads();
  for (int off = 1; off < 1024; off <<= 1) {
    int tv = (t >= off) ? s[t - off] : 0;
    __syncthreads();
    s[t] += tv;
    __syncthreads();
  }
  if (t < nb) bsum[t] = s[t] - v;  // exclusive
}

__global__ __launch_bounds__(256) void k_scanC(int* __restrict__ out, const int* __restrict__ bsum,
                                               int n, int total) {
  int base = blockIdx.x * 2048 + threadIdx.x * 8;
  int add = bsum[blockIdx.x];
#pragma unroll
  for (int i = 0; i < 8; ++i) { int idx = base + i; if (idx < n) out[idx] += add; }
  if (blockIdx.x == 0 && threadIdx.x == 0) out[n] = total;
}

// Pass 2: reorder chunk in LDS (bucket-major), all-lane coalesced write-out via
// 9-step binary search. 1024 threads, 70KB LDS -> 2 blocks/CU.
// hist_s values are offset by `sub` (0 for row section, E for col section).
__global__ __launch_bounds__(1024) void k_binR(const int* __restrict__ dst, const int* __restrict__ src,
                                               const int* __restrict__ hist_s, int* __restrict__ bin,
                                               int E, int nblocks, int nbuck, int sub) {
  __shared__ int lbuf[BIN_CHUNK];
  __shared__ int ls[512];
  __shared__ int cur[512];
  __shared__ int gbase[512];
  int t = threadIdx.x;
  if (t < 512) cur[t] = 0;
  __syncthreads();
  int blk0 = blockIdx.x * BIN_CHUNK;
  int eend = min(E, blk0 + BIN_CHUNK);
  int nent = eend - blk0;
  for (int e = blk0 + t; e < eend; e += 1024) atomicAdd(&cur[dst[e] >> BSH], 1);
  __syncthreads();
  int v = (t < 512) ? cur[t] : 0;
  if (t < 512) ls[t] = v;
  __syncthreads();
  for (int off = 1; off < 512; off <<= 1) {
    int x = (t >= off && t < 512) ? ls[t - off] : 0;
    __syncthreads();
    if (t < 512) ls[t] += x;
    __syncthreads();
  }
  if (t < 512) {
    int excl = ls[t] - v;
    ls[t] = excl;
    cur[t] = excl;
    gbase[t] = (t < nbuck) ? (hist_s[(size_t)t * nblocks + blockIdx.x] - sub) : 0;
  }
  __syncthreads();
  for (int e = blk0 + t; e < eend; e += 1024) {
    int d = dst[e];
    int slot = atomicAdd(&cur[d >> BSH], 1);
    lbuf[slot] = ((d & (NPB - 1)) << 18) | src[e];
  }
  __syncthreads();
  for (int i = t; i < nent; i += 1024) {
    int w = lbuf[i];
    int lo = 0;
#pragma unroll
    for (int sh = 256; sh > 0; sh >>= 1) {
      int mid = lo + sh;
      if (mid < 512 && ls[mid] <= i) lo = mid;
    }
    __builtin_nontemporal_store(w, &bin[gbase[lo] + (i - ls[lo])]);
  }
}

// Pass 3: one 1024-thread WG per 512-node bucket. Count + scan + LDS scatter + coalesced dump.
__global__ __launch_bounds__(1024) void k_buildcsr(const int* __restrict__ bin, const int* __restrict__ hist_s,
                                                   int* __restrict__ rowptr, int* __restrict__ csr,
                                                   float* __restrict__ dinv, int N, int Etot, int nblocks,
                                                   int sub) {
  __shared__ int cnt[NPB];
  __shared__ int sc[NPB];
  __shared__ int lbuf[CAP];
  int t = threadIdx.x;
  int b = blockIdx.x;
  int node0 = b << BSH;
  int nn = min(NPB, N - node0);
  int ebeg = hist_s[(size_t)b * nblocks] - sub;
  int eend = hist_s[(size_t)(b + 1) * nblocks] - sub;
  if (t < NPB) cnt[t] = (t < nn) ? 1 : 0;  // self loop
  __syncthreads();
  for (int p = ebeg + t; p < eend; p += 1024) atomicAdd(&cnt[bin[p] >> 18], 1);
  __syncthreads();
  int v = 0;
  if (t < NPB) { v = cnt[t]; sc[t] = v; }
  __syncthreads();
  for (int off = 1; off < NPB; off <<= 1) {
    int x = (t >= off && t < NPB) ? sc[t - off] : 0;
    __syncthreads();
    if (t < NPB) sc[t] += x;
    __syncthreads();
  }
  int excl = (t < NPB) ? (sc[t] - v) : 0;
  int cbase = ebeg + node0;
  if (t < nn) {
    rowptr[node0 + t] = cbase + excl;
    dinv[node0 + t] = rsqrtf((float)v);
  }
  int total2 = (eend - ebeg) + nn;
  bool stage = (total2 <= CAP);
  __syncthreads();
  if (t < NPB) cnt[t] = excl + ((t < nn) ? 1 : 0);
  if (t < nn) {
    if (stage) lbuf[excl] = node0 + t;
    else       csr[cbase + excl] = node0 + t;
  }
  __syncthreads();
  for (int p = ebeg + t; p < eend; p += 1024) {
    int w = bin[p];
    int slot = atomicAdd(&cnt[w >> 18], 1);
    if (stage) lbuf[slot] = w & 0x3FFFF;
    else       csr[cbase + slot] = w & 0x3FFFF;
  }
  __syncthreads();
  if (stage)
    for (int i = t; i < total2; i += 1024)
      __builtin_nontemporal_store(lbuf[i], &csr[cbase + i]);
  if (b == 0 && t == 0) rowptr[N] = Etot + N;
}

// ---------------- x @ W1 -> packed block-fp rows (pre-scaled by dinv_r) ----------------
__global__ __launch_bounds__(256) void k_xw(const float* __restrict__ x, const float* __restrict__ W1,
                                            const float* __restrict__ dinv, int4* __restrict__ tA, int n) {
  int tid = blockIdx.x * 256 + threadIdx.x;
  int sub = tid & 15;
  int rowStart = tid >> 4;
  int rowStride = (gridDim.x * 256) >> 4;
  float w[8][10];
#pragma unroll
  for (int jj = 0; jj < 8; ++jj)
#pragma unroll
    for (int k = 0; k < 10; ++k) w[jj][k] = W1[(sub * 8 + jj) * 10 + k];
  for (int row = rowStart; row < n; row += rowStride) {
    const float* xr = x + (size_t)row * 128 + sub * 8;
    float4 a = *(const float4*)xr;
    float4 b = *(const float4*)(xr + 4);
    float xv[8] = {a.x, a.y, a.z, a.w, b.x, b.y, b.z, b.w};
    float acc[10];
#pragma unroll
    for (int k = 0; k < 10; ++k) acc[k] = 0.f;
#pragma unroll
    for (int jj = 0; jj < 8; ++jj)
#pragma unroll
      for (int k = 0; k < 10; ++k) acc[k] = fmaf(xv[jj], w[jj][k], acc[k]);
#pragma unroll
    for (int off = 1; off < 16; off <<= 1)
#pragma unroll
      for (int k = 0; k < 10; ++k) acc[k] += __shfl_xor(acc[k], off);
    if (sub == 0) {
      float d = dinv[row];
      float o[10];
#pragma unroll
      for (int k = 0; k < 10; ++k) o[k] = acc[k] * d;
      tA[row] = pack10(o);
    }
  }
}

// ---------------- fused GCN layer (block-fp rows, 1 request/edge, 2x-unrolled ILP) ----------
template <bool USE_W>
__global__ __launch_bounds__(256) void k_agg10(const int4* __restrict__ tin, int4* __restrict__ tout,
                                               const int* __restrict__ csr, const int* __restrict__ rowptr,
                                               const float* __restrict__ dinv_d, const float* __restrict__ dnext,
                                               const float* __restrict__ W, const float* __restrict__ bias,
                                               int n) {
  int tid = blockIdx.x * 256 + threadIdx.x;
  int q = tid >> 4, lane = tid & 15;
  if (q >= n) return;
  int beg = rowptr[q], end = rowptr[q + 1];
  float acc[10];
#pragma unroll
  for (int k = 0; k < 10; ++k) acc[k] = 0.f;
  int p = beg + lane;
  for (; p + 16 < end; p += 32) {
    int s0 = csr[p];
    int s1 = csr[p + 16];
    int4 a0 = tin[s0];
    int4 a1 = tin[s1];
    unpack10_acc(a0, acc);
    unpack10_acc(a1, acc);
  }
  if (p < end) {
    int4 a = tin[csr[p]];
    unpack10_acc(a, acc);
  }
#pragma unroll
  for (int off = 1; off < 16; off <<= 1)
#pragma unroll
    for (int k = 0; k < 10; ++k) acc[k] += __shfl_xor(acc[k], off);
  float o = 0.f;
  if (lane < 10) {
    float dd = dinv_d[q];
    float dn = dnext[q];
    o = bias[lane];
    if (USE_W) {
#pragma unroll
      for (int m = 0; m < 10; ++m) o = fmaf(acc[m] * dd, W[m * 10 + lane], o);
    } else {
      o += acc[lane] * dd;
    }
    o = fmaxf(o, 0.f) * dn;
  }
  int l = threadIdx.x & 63;
  int qbase = l & 48;
  float oj[10];
#pragma unroll
  for (int k = 0; k < 10; ++k) oj[k] = __shfl(o, qbase + k, 64);
  if (lane == 0) tout[q] = pack10(oj);
}

// ---------------- output layer ----------------
__global__ __launch_bounds__(256) void k_agg1(const float* __restrict__ t5, float* __restrict__ probs,
                                              const int* __restrict__ csr, const int* __restrict__ rowptr,
                                              const float* __restrict__ dinv, const float* __restrict__ bo,
                                              int n) {
  int tid = blockIdx.x * 256 + threadIdx.x;
  int q = tid >> 4, lane = tid & 15;
  if (q >= n) return;
  int beg = rowptr[q], end = rowptr[q + 1];
  float acc = 0.f;
  int p = beg + lane;
  for (; p + 16 < end; p += 32) {
    float v0 = t5[csr[p]];
    float v1 = t5[csr[p + 16]];
    acc += v0 + v1;
  }
  if (p < end) acc += t5[csr[p]];
#pragma unroll
  for (int off = 1; off < 16; off <<= 1) acc += __shfl_xor(acc, off);
  if (lane == 0) probs[q] = fmaf(dinv[q], acc, bo[0]);
}

// ---------------- t5' = h4' @ Wo (stays pre-scaled), mean un-scales ----------------
__global__ __launch_bounds__(256) void k_t5mean(const int4* __restrict__ tA, const float* __restrict__ Wo,
                                                const float* __restrict__ dinv, float* __restrict__ t5,
                                                float* __restrict__ part, int n) {
  int tid = blockIdx.x * 256 + threadIdx.x;
  float wo[10];
#pragma unroll
  for (int k = 0; k < 10; ++k) wo[k] = Wo[k];
  float p[10];
#pragma unroll
  for (int k = 0; k < 10; ++k) p[k] = 0.f;
  for (int rowi = tid; rowi < n; rowi += 128 * 256) {
    int4 a = tA[rowi];
    float hv[10];
    unpack10(a, hv);
    float s = 0.f;
#pragma unroll
    for (int k = 0; k < 10; ++k) s = fmaf(hv[k], wo[k], s);
    t5[rowi] = s;
    float inv = 1.0f / dinv[rowi];  // un-scale for the mean
#pragma unroll
    for (int k = 0; k < 10; ++k) p[k] = fmaf(hv[k], inv, p[k]);
  }
#pragma unroll
  for (int off = 1; off < 64; off <<= 1)
#pragma unroll
    for (int k = 0; k < 10; ++k) p[k] += __shfl_xor(p[k], off);
  __shared__ float sp[4][10];
  int w = threadIdx.x >> 6, ln = threadIdx.x & 63;
  if (ln == 0) {
#pragma unroll
    for (int k = 0; k < 10; ++k) sp[w][k] = p[k];
  }
  __syncthreads();
  if (threadIdx.x < 10)
    part[blockIdx.x * 10 + threadIdx.x] =
        sp[0][threadIdx.x] + sp[1][threadIdx.x] + sp[2][threadIdx.x] + sp[3][threadIdx.x];
}

__global__ void k_finish(const float* __restrict__ part, const float* __restrict__ Wdn,
                         const float* __restrict__ bdn, const float* __restrict__ Wv,
                         const float* __restrict__ bv, float* __restrict__ out, int n, int nPart) {
  __shared__ float m[10];
  int t = threadIdx.x;
  if (t < 10) {
    float s = 0.f;
    for (int b = 0; b < nPart; ++b) s += part[b * 10 + t];
    m[t] = s / (float)n;
  }
  __syncthreads();
  if (t == 0) {
    float pn = bdn[0], vv = bv[0];
    for (int k = 0; k < 10; ++k) {
      pn = fmaf(m[k], Wdn[k], pn);
      vv = fmaf(m[k], Wv[k], vv);
    }
    out[n] = pn;
    out[n + 1] = vv;
  }
}

extern "C" void kernel_launch(void* const* d_in, const int* in_sizes, int n_in,
                              void* d_out, int out_size, void* d_ws, size_t ws_size,
                              hipStream_t stream) {
  const float* x  = (const float*)d_in[0];
  const int* ei   = (const int*)d_in[1];
  const float* W1 = (const float*)d_in[2];
  const float* b1 = (const float*)d_in[3];
  const float* W2 = (const float*)d_in[4];
  const float* b2 = (const float*)d_in[5];
  const float* Wp = (const float*)d_in[6];
  const float* bp = (const float*)d_in[7];
  const float* W3 = (const float*)d_in[8];
  const float* b3 = (const float*)d_in[9];
  const float* Wo = (const float*)d_in[10];
  const float* bo = (const float*)d_in[11];
  const float* Wdn = (const float*)d_in[12];
  const float* bdn = (const float*)d_in[13];
  const float* Wv = (const float*)d_in[14];
  const float* bv = (const float*)d_in[15];

  int N = in_sizes[0] / 128;
  int E = in_sizes[1] / 2;
  const int* row = ei;
  const int* colv = ei + E;
  float* out = (float*)d_out;
  int nbuck = (N + NPB - 1) >> BSH;            // <= 512
  int bb = (E + BIN_CHUNK - 1) / BIN_CHUNK;
  size_t M = (size_t)nbuck * bb;               // per-direction hist entries
  int n2 = (int)(2 * M);                       // concatenated [row|col] hist

  char* ws = (char*)d_ws;
  size_t off = 0;
  auto alloc = [&](size_t b) -> void* {
    void* p = ws + off;
    off += (b + 255) & ~(size_t)255;
    return p;
  };
  int* csr_r = (int*)alloc((size_t)(E + N) * 4);
  int* csr_c = (int*)alloc((size_t)(E + N) * 4);
  int* rp_r = (int*)alloc((size_t)(N + 1) * 4);
  int* rp_c = (int*)alloc((size_t)(N + 1) * 4);
  float* dinv_r = (float*)alloc((size_t)N * 4);
  float* dinv_c = (float*)alloc((size_t)N * 4);
  int* hist = (int*)alloc((2 * M + 1) * 4);
  int* bsum = (int*)alloc(4096);
  // union region: bin (build phase) overlaps packed hidden-state arrays (compute phase)
  size_t binB = (size_t)E * 4;
  size_t tB_ = (size_t)N * 36 + 8192;   // tA_a 16N + tA_b 16N + t5 4N + part
  char* region = (char*)alloc(binB > tB_ ? binB : tB_);
  int* bin = (int*)region;
  int4* tA_a = (int4*)region;                               // 16N
  int4* tA_b = (int4*)(region + (size_t)N * 16);            // 16N
  float* t5  = (float*)(region + (size_t)N * 32);           // 4N
  float* part = (float*)(region + (size_t)N * 36);
  if (off > ws_size) {
    fprintf(stderr, "WS too small: need %zu have %zu\n", off, ws_size);
    return;
  }

  int sb2 = (n2 + 2047) / 2048;
  int ab = (int)(((size_t)N * 16 + 255) / 256);

  // fused histograms for both directions + one scan pipeline
  k_histpb2<<<bb, 1024, 0, stream>>>(row, colv, hist, E, bb, nbuck, (int)M);
  k_scanA<<<sb2, 256, 0, stream>>>(hist, hist, bsum, n2);
  k_scanB<<<1, 1024, 0, stream>>>(bsum, sb2);
  k_scanC<<<sb2, 256, 0, stream>>>(hist, bsum, n2, 2 * E);
  // row-CSR (dst=row, src=col): hist section [0, M), sub=0
  k_binR<<<bb, 1024, 0, stream>>>(row, colv, hist, bin, E, bb, nbuck, 0);
  k_buildcsr<<<nbuck, 1024, 0, stream>>>(bin, hist, rp_r, csr_r, dinv_r, N, E, bb, 0);
  // col-CSR (dst=col, src=row): hist section [M, 2M), values offset by E
  k_binR<<<bb, 1024, 0, stream>>>(colv, row, hist + M, bin, E, bb, nbuck, E);
  k_buildcsr<<<nbuck, 1024, 0, stream>>>(bin, hist + M, rp_c, csr_c, dinv_c, N, E, bb, E);

  // network (hidden rows packed block-fp 16B, pre-scaled by the NEXT consumer's dinv)
  k_xw<<<2048, 256, 0, stream>>>(x, W1, dinv_r, tA_a, N);
  k_agg10<false><<<ab, 256, 0, stream>>>(tA_a, tA_b, csr_r, rp_r, dinv_r, dinv_r, nullptr, b1, N);
  k_agg10<true><<<ab, 256, 0, stream>>>(tA_b, tA_a, csr_r, rp_r, dinv_r, dinv_c, W2, b2, N);
  k_agg10<true><<<ab, 256, 0, stream>>>(tA_a, tA_b, csr_c, rp_c, dinv_c, dinv_r, Wp, bp, N);
  k_agg10<true><<<ab, 256, 0, stream>>>(tA_b, tA_a, csr_r, rp_r, dinv_r, dinv_r, W3, b3, N);
  k_t5mean<<<128, 256, 0, stream>>>(tA_a, Wo, dinv_r, t5, part, N);
  k_agg1<<<ab, 256, 0, stream>>>(t5, out, csr_r, rp_r, dinv_r, bo, N);
  k_finish<<<1, 64, 0, stream>>>(part, Wdn, bdn, Wv, bv, out, N, 128);
}